// Round 13
// baseline (678.517 us; speedup 1.0000x reference)
//
#include <hip/hip_runtime.h>
#include <math.h>

#define N_VAR 8192
#define N_CHK 4096
#define DV 3
#define N_EDGE (N_VAR * DV)
#define BATCH 128
#define T_ITERS 30
#define ELLW 24
#define SLOT_MAX (N_EDGE + 3 * N_CHK)   /* 36864: sum of padded degs bound */

#define LOG2E 1.44269504088896340736f
#define LN2   0.69314718055994530942f

typedef _Float16 h4 __attribute__((ext_vector_type(4)));
typedef _Float16 h2 __attribute__((ext_vector_type(2)));

// tanh(x/2), sign preserved, |t| floored at 1e-7 (matches reference clamp);
// x pre-clipped to [-15,15]
__device__ __forceinline__ float tanh_half(float x) {
    float ex = __builtin_amdgcn_exp2f(x * LOG2E);              // e^x
    float t = 1.0f - 2.0f * __builtin_amdgcn_rcpf(ex + 1.0f);
    float s = (x < 0.0f) ? -1.0f : 1.0f;
    return s * fmaxf(fabsf(t), 1e-7f);
}

// 2*atanh(clip(p)) — reference's clip(-1+eps, 1-eps) then 2 atanh (validated)
__device__ __forceinline__ float atanh2(float p) {
    const float lim = 1.0f - 1e-7f;
    p = fminf(fmaxf(p, -lim), lim);
    return (__builtin_amdgcn_logf(1.0f + p) -
            __builtin_amdgcn_logf(1.0f - p)) * LN2;
}

// ---------------- graph build ------------------------------------------------

__global__ void k_ell_scatter(const int* __restrict__ edge_chk,
                              int* __restrict__ deg_arr, int* __restrict__ ell_e) {
    int e = blockIdx.x * blockDim.x + threadIdx.x;
    if (e < N_EDGE) {
        int c = edge_chk[e];
        int pos = atomicAdd(&deg_arr[c], 1);
        if (pos < ELLW) ell_e[c * ELLW + pos] = e;   // store EDGE id
    }
}

// single-block: histogram + bucket prefix + degree-sorted placement (LDS state)
__global__ __launch_bounds__(1024) void k_sort(
        const int* __restrict__ deg_arr,
        int* __restrict__ s_desc_g,      // N_CHK sorted check descriptors
        int* __restrict__ chk_base) {    // N_CHK per-check padded slot base
    __shared__ int hist[32], cursor_s[32], bbase[32], soff[32];
    const int tid = threadIdx.x;
    if (tid < 32) { hist[tid] = 0; cursor_s[tid] = 0; }
    __syncthreads();
    for (int c = tid; c < N_CHK; c += 1024) {
        int d = deg_arr[c]; if (d > ELLW) d = ELLW;
        atomicAdd(&hist[d], 1);
    }
    __syncthreads();
    if (tid == 0) {
        int cb = 0, sb = 0;
        for (int d = 0; d <= ELLW; ++d) {
            bbase[d] = cb; soff[d] = sb;
            int pd = (d == 0) ? 0 : ((d + 3) & ~3);
            cb += hist[d];
            sb += hist[d] * pd;
        }
    }
    __syncthreads();
    for (int c = tid; c < N_CHK; c += 1024) {
        int d = deg_arr[c]; if (d > ELLW) d = ELLW;
        int pd = (d + 3) & ~3;
        int pos = atomicAdd(&cursor_s[d], 1);
        int i = bbase[d] + pos;
        int base = soff[d] + pos * pd;
        s_desc_g[i] = (base << 5) | d;
        chk_base[c] = base;
    }
}

// slot_e[e] = padded compact slot of edge e
__global__ void k_slotmap2(const int* __restrict__ ell_e,
                           const int* __restrict__ deg_arr,
                           const int* __restrict__ chk_base,
                           int* __restrict__ slot_e) {
    int gid = blockIdx.x * 256 + threadIdx.x;
    if (gid < N_CHK * ELLW) {
        int c = gid / ELLW;
        int j = gid - c * ELLW;
        int d = deg_arr[c]; if (d > ELLW) d = ELLW;
        if (j < d) slot_e[ell_e[gid]] = chk_base[c] + j;
    }
}

// slot4[v] = slots of v's 3 edges
__global__ void k_slot4(const int* __restrict__ slot_e, int4* __restrict__ slot4) {
    int v = blockIdx.x * 256 + threadIdx.x;
    if (v < N_VAR) {
        int4 s;
        s.x = slot_e[3 * v + 0];
        s.y = slot_e[3 * v + 1];
        s.z = slot_e[3 * v + 2];
        s.w = 0;
        slot4[v] = s;
    }
}

// ---------------- persistent per-batch-element BP ----------------------------
// One block per batch element. In-place LDS msg (72 KB): phase A reads c2v,
// writes x to the same slot (owner-exclusive); phase B b64 vector ops on
// 8B-aligned padded check rows, degree-sorted -> wave-uniform deg.
// v2c in f32 registers. Posterior slices stored fp16 to outT (t,b,v).
// Phase B extrinsic via suffix/prefix products (no per-edge division).

__global__ __launch_bounds__(1024) void k_bp2(
        const float* __restrict__ chn,
        const float* __restrict__ gamma_logit,
        const int4* __restrict__ slot4,
        const int* __restrict__ s_desc_g,
        _Float16* __restrict__ outT) {      // (T, BATCH, N_VAR) fp16
    __shared__ __align__(16) _Float16 msg[SLOT_MAX];
    const int b = blockIdx.x;
    const int tid = threadIdx.x;

    for (int i = tid; i < SLOT_MAX; i += 1024) msg[i] = (_Float16)0.0f;

    const float g = 1.0f / (1.0f + __builtin_amdgcn_exp2f(-gamma_logit[0] * LOG2E));
    const float om = 1.0f - g;
    const float AT1 = atanh2(1.0f);         // deg-1 extrinsic constant

    float chn_r[8];
    float v2c_r[8][3];
    int4 s4r[8];
    int desc_r[4];
#pragma unroll
    for (int k = 0; k < 8; ++k) {
        int v = tid + k * 1024;
        chn_r[k] = chn[(size_t)v * BATCH + b];
        s4r[k] = slot4[v];
        v2c_r[k][0] = 0.0f; v2c_r[k][1] = 0.0f; v2c_r[k][2] = 0.0f;
    }
#pragma unroll
    for (int m = 0; m < 4; ++m) desc_r[m] = s_desc_g[m * 1024 + tid];
    __syncthreads();

    const size_t SLICE = (size_t)N_VAR * BATCH;

    for (int t = 0; t < T_ITERS; ++t) {
        // ---- phase A: variables (8 per thread), in-place c2v -> x ----
#pragma unroll
        for (int k = 0; k < 8; ++k) {
            int v = tid + k * 1024;
            int4 s4 = s4r[k];
            float c0 = (float)msg[s4.x];
            float c1 = (float)msg[s4.y];
            float c2 = (float)msg[s4.z];
            float post = chn_r[k] + c0 + c1 + c2;
            if (t > 0) {
                __builtin_nontemporal_store((_Float16)post,
                    &outT[(size_t)(t - 1) * SLICE + (size_t)b * N_VAR + v]);
            }
            float vn0 = g * (post - c0) + om * v2c_r[k][0];
            float vn1 = g * (post - c1) + om * v2c_r[k][1];
            float vn2 = g * (post - c2) + om * v2c_r[k][2];
            v2c_r[k][0] = vn0; v2c_r[k][1] = vn1; v2c_r[k][2] = vn2;
            msg[s4.x] = (_Float16)fminf(fmaxf(vn0, -15.0f), 15.0f);
            msg[s4.y] = (_Float16)fminf(fmaxf(vn1, -15.0f), 15.0f);
            msg[s4.z] = (_Float16)fminf(fmaxf(vn2, -15.0f), 15.0f);
        }
        __syncthreads();

        // ---- phase B: checks (4 per thread, degree-sorted) ----
#pragma unroll
        for (int m = 0; m < 4; ++m) {
            int desc = desc_r[m];
            int base = desc >> 5;
            int deg = desc & 31;
            if (deg == 1) {
                msg[base] = (_Float16)AT1;
            } else if (deg > 1) {
                int nw = (deg + 3) >> 2;
                h4 raw[6];
#pragma unroll
                for (int w = 0; w < 6; ++w)
                    if (w < nw) raw[w] = *(const h4*)&msg[base + 4 * w];
                float tv[ELLW];
#pragma unroll
                for (int j = 0; j < ELLW; ++j)
                    if (j < deg) tv[j] = tanh_half((float)raw[j >> 2][j & 3]);
                // suffix products: ext[j] = prod_{k>j} tv[k]
                float ext[ELLW];
                float run = 1.0f;
#pragma unroll
                for (int j = ELLW - 1; j >= 0; --j)
                    if (j < deg) { ext[j] = run; run *= tv[j]; }
                // prefix sweep + emit (no division)
                float pfx = 1.0f;
#pragma unroll
                for (int w = 0; w < 6; ++w)
                    if (w < nw) {
                        h4 out_w;
#pragma unroll
                        for (int q = 0; q < 4; ++q) {
                            int j = 4 * w + q;
                            float m2 = 0.0f;
                            if (j < deg) {
                                float p = pfx * ext[j];
                                pfx *= tv[j];
                                m2 = atanh2(p);
                            }
                            out_w[q] = (_Float16)m2;
                        }
                        *(h4*)&msg[base + 4 * w] = out_w;
                    }
            }
        }
        __syncthreads();
    }

    // ---- final posterior row (after last check update) ----
#pragma unroll
    for (int k = 0; k < 8; ++k) {
        int v = tid + k * 1024;
        int4 s4 = s4r[k];
        float post = chn_r[k] + (float)msg[s4.x] + (float)msg[s4.y] +
                     (float)msg[s4.z];
        __builtin_nontemporal_store((_Float16)post,
            &outT[(size_t)(T_ITERS - 1) * SLICE + (size_t)b * N_VAR + v]);
    }
}

// ---------------- transpose (T,B,V) fp16 -> (T,V,B) f32 ---------------------
// 64v x 32b tiles; h2 reads (4B/lane coalesced), f32 coalesced writes.

__global__ __launch_bounds__(256) void k_transpose(
        const _Float16* __restrict__ src, float* __restrict__ dst) {
    __shared__ float tile[64][33];
    int t = blockIdx.z;
    int v0 = blockIdx.x * 64;
    int b0 = blockIdx.y * 32;
    int lx = threadIdx.x;            // 32 wide
    int ly = threadIdx.y;            // 8
    const _Float16* s = src + (size_t)t * N_VAR * BATCH;
    float* d = dst + (size_t)t * N_VAR * BATCH;
#pragma unroll
    for (int i = 0; i < 32; i += 8) {
        int bl = ly + i;
        h2 pv = *(const h2*)&s[(size_t)(b0 + bl) * N_VAR + v0 + 2 * lx];
        tile[2 * lx + 0][bl] = (float)pv.x;
        tile[2 * lx + 1][bl] = (float)pv.y;
    }
    __syncthreads();
#pragma unroll
    for (int j = 0; j < 64; j += 8)
        __builtin_nontemporal_store(tile[j + ly][lx],
            &d[(size_t)(v0 + j + ly) * BATCH + b0 + lx]);
}

// ---------------- Launch ---------------------------------------------------

extern "C" void kernel_launch(void* const* d_in, const int* in_sizes, int n_in,
                              void* d_out, int out_size, void* d_ws, size_t ws_size,
                              hipStream_t stream) {
    const float* chn         = (const float*)d_in[0];
    const float* gamma_logit = (const float*)d_in[1];
    // d_in[2] = edge_var (deterministic: e/3) — not needed
    const int* edge_chk      = (const int*)d_in[3];
    float* out = (float*)d_out;

    // workspace layout
    int4* slot4   = (int4*)d_ws;                           // N_VAR
    int* slot_e   = (int*)(slot4 + N_VAR);                 // N_EDGE
    int* ell_e    = slot_e + N_EDGE;                       // N_CHK*ELLW
    int* deg_arr  = ell_e + (size_t)N_CHK * ELLW;          // N_CHK
    int* chk_base = deg_arr + N_CHK;                       // N_CHK
    int* s_desc_g = chk_base + N_CHK;                      // N_CHK
    size_t table_bytes = (char*)(s_desc_g + N_CHK) - (char*)d_ws;
    size_t outT_off = (table_bytes + 255) & ~(size_t)255;
    _Float16* outT = (_Float16*)((char*)d_ws + outT_off);  // T*SLICE fp16

    (void)hipMemsetAsync(deg_arr, 0, N_CHK * sizeof(int), stream);

    k_ell_scatter<<<(N_EDGE + 255) / 256, 256, 0, stream>>>(edge_chk, deg_arr,
                                                            ell_e);
    k_sort<<<1, 1024, 0, stream>>>(deg_arr, s_desc_g, chk_base);
    k_slotmap2<<<(N_CHK * ELLW + 255) / 256, 256, 0, stream>>>(ell_e, deg_arr,
                                                               chk_base, slot_e);
    k_slot4<<<N_VAR / 256, 256, 0, stream>>>(slot_e, slot4);

    k_bp2<<<BATCH, 1024, 0, stream>>>(chn, gamma_logit, slot4, s_desc_g, outT);

    dim3 tg(N_VAR / 64, BATCH / 32, T_ITERS);
    dim3 tb(32, 8, 1);
    k_transpose<<<tg, tb, 0, stream>>>(outT, out);
}

// Round 14
// 514.344 us; speedup vs baseline: 1.3192x; 1.3192x over previous
//
#include <hip/hip_runtime.h>
#include <math.h>

#define N_VAR 8192
#define N_CHK 4096
#define DV 3
#define N_EDGE (N_VAR * DV)
#define BATCH 128
#define T_ITERS 30
#define ELLW 24
#define SLOT_MAX (N_EDGE + 3 * N_CHK)   /* 36864: sum of padded degs bound */

#define LOG2E 1.44269504088896340736f
#define LN2   0.69314718055994530942f

typedef _Float16 h4 __attribute__((ext_vector_type(4)));
typedef _Float16 h2 __attribute__((ext_vector_type(2)));

// tanh(x/2), sign preserved, |t| floored at 1e-7 (matches reference clamp);
// x pre-clipped to [-15,15]
__device__ __forceinline__ float tanh_half(float x) {
    float ex = __builtin_amdgcn_exp2f(x * LOG2E);              // e^x
    float t = 1.0f - 2.0f * __builtin_amdgcn_rcpf(ex + 1.0f);
    float s = (x < 0.0f) ? -1.0f : 1.0f;
    return s * fmaxf(fabsf(t), 1e-7f);
}

// 2*atanh(clip(p)) — reference's clip(-1+eps, 1-eps) then 2 atanh (validated)
__device__ __forceinline__ float atanh2(float p) {
    const float lim = 1.0f - 1e-7f;
    p = fminf(fmaxf(p, -lim), lim);
    return (__builtin_amdgcn_logf(1.0f + p) -
            __builtin_amdgcn_logf(1.0f - p)) * LN2;
}

// Newton-refined reciprocal (validated R8/R9/R11/R12, absmax 0.125)
__device__ __forceinline__ float rcp_nr(float x) {
    float r = __builtin_amdgcn_rcpf(x);
    return r * (2.0f - x * r);
}

// ---------------- graph build ------------------------------------------------

__global__ void k_ell_scatter(const int* __restrict__ edge_chk,
                              int* __restrict__ deg_arr, int* __restrict__ ell_e) {
    int e = blockIdx.x * blockDim.x + threadIdx.x;
    if (e < N_EDGE) {
        int c = edge_chk[e];
        int pos = atomicAdd(&deg_arr[c], 1);
        if (pos < ELLW) ell_e[c * ELLW + pos] = e;   // store EDGE id
    }
}

// single-block: histogram + bucket prefix + degree-sorted placement (LDS state)
__global__ __launch_bounds__(1024) void k_sort(
        const int* __restrict__ deg_arr,
        int* __restrict__ s_desc_g,      // N_CHK sorted check descriptors
        int* __restrict__ chk_base) {    // N_CHK per-check padded slot base
    __shared__ int hist[32], cursor_s[32], bbase[32], soff[32];
    const int tid = threadIdx.x;
    if (tid < 32) { hist[tid] = 0; cursor_s[tid] = 0; }
    __syncthreads();
    for (int c = tid; c < N_CHK; c += 1024) {
        int d = deg_arr[c]; if (d > ELLW) d = ELLW;
        atomicAdd(&hist[d], 1);
    }
    __syncthreads();
    if (tid == 0) {
        int cb = 0, sb = 0;
        for (int d = 0; d <= ELLW; ++d) {
            bbase[d] = cb; soff[d] = sb;
            int pd = (d == 0) ? 0 : ((d + 3) & ~3);
            cb += hist[d];
            sb += hist[d] * pd;
        }
    }
    __syncthreads();
    for (int c = tid; c < N_CHK; c += 1024) {
        int d = deg_arr[c]; if (d > ELLW) d = ELLW;
        int pd = (d + 3) & ~3;
        int pos = atomicAdd(&cursor_s[d], 1);
        int i = bbase[d] + pos;
        int base = soff[d] + pos * pd;
        s_desc_g[i] = (base << 5) | d;
        chk_base[c] = base;
    }
}

// slot_e[e] = padded compact slot of edge e
__global__ void k_slotmap2(const int* __restrict__ ell_e,
                           const int* __restrict__ deg_arr,
                           const int* __restrict__ chk_base,
                           int* __restrict__ slot_e) {
    int gid = blockIdx.x * 256 + threadIdx.x;
    if (gid < N_CHK * ELLW) {
        int c = gid / ELLW;
        int j = gid - c * ELLW;
        int d = deg_arr[c]; if (d > ELLW) d = ELLW;
        if (j < d) slot_e[ell_e[gid]] = chk_base[c] + j;
    }
}

// slot4[v] = slots of v's 3 edges
__global__ void k_slot4(const int* __restrict__ slot_e, int4* __restrict__ slot4) {
    int v = blockIdx.x * 256 + threadIdx.x;
    if (v < N_VAR) {
        int4 s;
        s.x = slot_e[3 * v + 0];
        s.y = slot_e[3 * v + 1];
        s.z = slot_e[3 * v + 2];
        s.w = 0;
        slot4[v] = s;
    }
}

// ---------------- persistent per-batch-element BP (R9/R11/R12-validated) ----
// One block per batch element. In-place LDS msg (72 KB): phase A reads c2v,
// writes x to the same slot (owner-exclusive); phase B b64 vector ops on
// 8B-aligned padded check rows, degree-sorted -> wave-uniform deg.
// v2c in f32 registers. Posterior slices stored fp16 to outT (t,b,v).
// Phase B extrinsic via P * rcp_nr(t_j): fits the 64-VGPR launch-bounds cap
// (suffix/prefix ext[24] spills to scratch at this block size — R13, +167us).

__global__ __launch_bounds__(1024) void k_bp2(
        const float* __restrict__ chn,
        const float* __restrict__ gamma_logit,
        const int4* __restrict__ slot4,
        const int* __restrict__ s_desc_g,
        _Float16* __restrict__ outT) {      // (T, BATCH, N_VAR) fp16
    __shared__ __align__(16) _Float16 msg[SLOT_MAX];
    const int b = blockIdx.x;
    const int tid = threadIdx.x;

    for (int i = tid; i < SLOT_MAX; i += 1024) msg[i] = (_Float16)0.0f;

    const float g = 1.0f / (1.0f + __builtin_amdgcn_exp2f(-gamma_logit[0] * LOG2E));
    const float om = 1.0f - g;
    const float AT1 = atanh2(1.0f);         // deg-1 extrinsic constant

    float chn_r[8];
    float v2c_r[8][3];
    int4 s4r[8];
    int desc_r[4];
#pragma unroll
    for (int k = 0; k < 8; ++k) {
        int v = tid + k * 1024;
        chn_r[k] = chn[(size_t)v * BATCH + b];
        s4r[k] = slot4[v];
        v2c_r[k][0] = 0.0f; v2c_r[k][1] = 0.0f; v2c_r[k][2] = 0.0f;
    }
#pragma unroll
    for (int m = 0; m < 4; ++m) desc_r[m] = s_desc_g[m * 1024 + tid];
    __syncthreads();

    const size_t SLICE = (size_t)N_VAR * BATCH;

    for (int t = 0; t < T_ITERS; ++t) {
        // ---- phase A: variables (8 per thread), in-place c2v -> x ----
#pragma unroll
        for (int k = 0; k < 8; ++k) {
            int v = tid + k * 1024;
            int4 s4 = s4r[k];
            float c0 = (float)msg[s4.x];
            float c1 = (float)msg[s4.y];
            float c2 = (float)msg[s4.z];
            float post = chn_r[k] + c0 + c1 + c2;
            if (t > 0) {
                __builtin_nontemporal_store((_Float16)post,
                    &outT[(size_t)(t - 1) * SLICE + (size_t)b * N_VAR + v]);
            }
            float vn0 = g * (post - c0) + om * v2c_r[k][0];
            float vn1 = g * (post - c1) + om * v2c_r[k][1];
            float vn2 = g * (post - c2) + om * v2c_r[k][2];
            v2c_r[k][0] = vn0; v2c_r[k][1] = vn1; v2c_r[k][2] = vn2;
            msg[s4.x] = (_Float16)fminf(fmaxf(vn0, -15.0f), 15.0f);
            msg[s4.y] = (_Float16)fminf(fmaxf(vn1, -15.0f), 15.0f);
            msg[s4.z] = (_Float16)fminf(fmaxf(vn2, -15.0f), 15.0f);
        }
        __syncthreads();

        // ---- phase B: checks (4 per thread, degree-sorted) ----
#pragma unroll
        for (int m = 0; m < 4; ++m) {
            int desc = desc_r[m];
            int base = desc >> 5;
            int deg = desc & 31;
            if (deg == 1) {
                msg[base] = (_Float16)AT1;
            } else if (deg > 1) {
                int nw = (deg + 3) >> 2;
                h4 raw[6];
#pragma unroll
                for (int w = 0; w < 6; ++w)
                    if (w < nw) raw[w] = *(const h4*)&msg[base + 4 * w];
                float tv[ELLW];
                float P = 1.0f;
#pragma unroll
                for (int j = 0; j < ELLW; ++j)
                    if (j < deg) {
                        tv[j] = tanh_half((float)raw[j >> 2][j & 3]);
                        P *= tv[j];
                    }
#pragma unroll
                for (int w = 0; w < 6; ++w)
                    if (w < nw) {
                        h4 out_w;
#pragma unroll
                        for (int q = 0; q < 4; ++q) {
                            int j = 4 * w + q;
                            float m2 = (j < deg) ? atanh2(P * rcp_nr(tv[j])) : 0.0f;
                            out_w[q] = (_Float16)m2;
                        }
                        *(h4*)&msg[base + 4 * w] = out_w;
                    }
            }
        }
        __syncthreads();
    }

    // ---- final posterior row (after last check update) ----
#pragma unroll
    for (int k = 0; k < 8; ++k) {
        int v = tid + k * 1024;
        int4 s4 = s4r[k];
        float post = chn_r[k] + (float)msg[s4.x] + (float)msg[s4.y] +
                     (float)msg[s4.z];
        __builtin_nontemporal_store((_Float16)post,
            &outT[(size_t)(T_ITERS - 1) * SLICE + (size_t)b * N_VAR + v]);
    }
}

// ---------------- transpose (T,B,V) fp16 -> (T,V,B) f32 ---------------------
// 64v x 32b tiles; h2 reads (4B/lane coalesced), f32 coalesced writes.

__global__ __launch_bounds__(256) void k_transpose(
        const _Float16* __restrict__ src, float* __restrict__ dst) {
    __shared__ float tile[64][33];
    int t = blockIdx.z;
    int v0 = blockIdx.x * 64;
    int b0 = blockIdx.y * 32;
    int lx = threadIdx.x;            // 32 wide
    int ly = threadIdx.y;            // 8
    const _Float16* s = src + (size_t)t * N_VAR * BATCH;
    float* d = dst + (size_t)t * N_VAR * BATCH;
#pragma unroll
    for (int i = 0; i < 32; i += 8) {
        int bl = ly + i;
        h2 pv = *(const h2*)&s[(size_t)(b0 + bl) * N_VAR + v0 + 2 * lx];
        tile[2 * lx + 0][bl] = (float)pv.x;
        tile[2 * lx + 1][bl] = (float)pv.y;
    }
    __syncthreads();
#pragma unroll
    for (int j = 0; j < 64; j += 8)
        __builtin_nontemporal_store(tile[j + ly][lx],
            &d[(size_t)(v0 + j + ly) * BATCH + b0 + lx]);
}

// ---------------- Launch ---------------------------------------------------

extern "C" void kernel_launch(void* const* d_in, const int* in_sizes, int n_in,
                              void* d_out, int out_size, void* d_ws, size_t ws_size,
                              hipStream_t stream) {
    const float* chn         = (const float*)d_in[0];
    const float* gamma_logit = (const float*)d_in[1];
    // d_in[2] = edge_var (deterministic: e/3) — not needed
    const int* edge_chk      = (const int*)d_in[3];
    float* out = (float*)d_out;

    // workspace layout
    int4* slot4   = (int4*)d_ws;                           // N_VAR
    int* slot_e   = (int*)(slot4 + N_VAR);                 // N_EDGE
    int* ell_e    = slot_e + N_EDGE;                       // N_CHK*ELLW
    int* deg_arr  = ell_e + (size_t)N_CHK * ELLW;          // N_CHK
    int* chk_base = deg_arr + N_CHK;                       // N_CHK
    int* s_desc_g = chk_base + N_CHK;                      // N_CHK
    size_t table_bytes = (char*)(s_desc_g + N_CHK) - (char*)d_ws;
    size_t outT_off = (table_bytes + 255) & ~(size_t)255;
    _Float16* outT = (_Float16*)((char*)d_ws + outT_off);  // T*SLICE fp16

    (void)hipMemsetAsync(deg_arr, 0, N_CHK * sizeof(int), stream);

    k_ell_scatter<<<(N_EDGE + 255) / 256, 256, 0, stream>>>(edge_chk, deg_arr,
                                                            ell_e);
    k_sort<<<1, 1024, 0, stream>>>(deg_arr, s_desc_g, chk_base);
    k_slotmap2<<<(N_CHK * ELLW + 255) / 256, 256, 0, stream>>>(ell_e, deg_arr,
                                                               chk_base, slot_e);
    k_slot4<<<N_VAR / 256, 256, 0, stream>>>(slot_e, slot4);

    k_bp2<<<BATCH, 1024, 0, stream>>>(chn, gamma_logit, slot4, s_desc_g, outT);

    dim3 tg(N_VAR / 64, BATCH / 32, T_ITERS);
    dim3 tb(32, 8, 1);
    k_transpose<<<tg, tb, 0, stream>>>(outT, out);
}